// Round 19
// baseline (403.125 us; speedup 1.0000x reference)
//
#include <hip/hip_runtime.h>
#include <hip/hip_bf16.h>

#define NN 100000      // nodes
#define EE 1600000     // edges
#define HD 64
#define SLOPE 0.01f
#define BN_EPS 1e-5f
#define TS_BF 144
#define TS_F32 272
#define NTILE (NN / 16)   // 6250

// bucketed CSR build
#define BSHIFT 9
#define BSIZE 512
#define NBUCK ((NN + BSIZE - 1) / BSIZE)   // 196
#define BCAP 16384
#define CHUNKE 8192
#define NBLKA ((EE + CHUNKE - 1) / CHUNKE) // 196

typedef __attribute__((ext_vector_type(8))) short short8;
typedef __attribute__((ext_vector_type(8))) __bf16 bf16x8;
typedef __attribute__((ext_vector_type(4))) float f32x4;

__device__ __forceinline__ float lrelu(float v) { return v > 0.f ? v : SLOPE * v; }
__device__ __forceinline__ float bflo(unsigned u) { return __uint_as_float(u << 16); }
__device__ __forceinline__ float bfhi(unsigned u) { return __uint_as_float(u & 0xFFFF0000u); }
__device__ __forceinline__ unsigned short f2bf(float f) {
    __hip_bfloat16 hb = __float2bfloat16(f);
    return *reinterpret_cast<unsigned short*>(&hb);
}

// ---------------- CSR build: bucketed two-pass counting sort ----------------
__global__ __launch_bounds__(256) void k_binit(int* __restrict__ bcursor) {
    int t = threadIdx.x;
    if (t < NBUCK) bcursor[t] = t * BCAP;
}

__global__ __launch_bounds__(256) void k_bucketa(const int* __restrict__ src,
                                                 const int* __restrict__ dst,
                                                 int* __restrict__ bcursor,
                                                 int* __restrict__ staging) {
    __shared__ int hist[NBUCK], base_l[NBUCK], cur_l[NBUCK];
    int tid = threadIdx.x;
    int base = blockIdx.x * CHUNKE;
    int nE = min(CHUNKE, EE - base);
    for (int i = tid; i < NBUCK; i += 256) hist[i] = 0;
    __syncthreads();
    for (int k = tid; k < nE; k += 256)
        atomicAdd(&hist[dst[base + k] >> BSHIFT], 1);
    __syncthreads();
    for (int i = tid; i < NBUCK; i += 256) {
        int h = hist[i];
        base_l[i] = h ? atomicAdd(&bcursor[i], h) : 0;
        cur_l[i] = 0;
    }
    __syncthreads();
    for (int k = tid; k < nE; k += 256) {
        int d = dst[base + k];
        int s = src[base + k];
        int b = d >> BSHIFT;
        int off = atomicAdd(&cur_l[b], 1);
        staging[base_l[b] + off] = (s << BSHIFT) | (d & (BSIZE - 1));
    }
}

__global__ __launch_bounds__(256) void k_bscan(const int* __restrict__ bcursor,
                                               int* __restrict__ bbase,
                                               int* __restrict__ row_ptr) {
    __shared__ int sc[256], cnt[256];
    int tid = threadIdx.x;
    int c = (tid < NBUCK) ? (bcursor[tid] - tid * BCAP) : 0;
    cnt[tid] = c;
    sc[tid] = c;
    __syncthreads();
    for (int s = 1; s < 256; s <<= 1) {
        int v = (tid >= s) ? sc[tid - s] : 0;
        __syncthreads();
        sc[tid] += v;
        __syncthreads();
    }
    if (tid < NBUCK) bbase[tid] = sc[tid] - cnt[tid];
    if (tid == 0) row_ptr[NN] = EE;
}

__global__ __launch_bounds__(256) void k_bucketb(const int* __restrict__ staging,
                                                 const int* __restrict__ bcursor,
                                                 const int* __restrict__ bbase,
                                                 int* __restrict__ row_ptr,
                                                 int* __restrict__ csr) {
    __shared__ int cnt[BSIZE], sc[BSIZE], cur[BSIZE];
    int b = blockIdx.x, tid = threadIdx.x;
    int cnt_e = bcursor[b] - b * BCAP;
    int sbase = b * BCAP;
    int n0 = b * BSIZE;
    int nn = min(BSIZE, NN - n0);
    int bb = bbase[b];
    cnt[tid] = 0;
    cnt[tid + 256] = 0;
    __syncthreads();
    for (int i = tid; i < cnt_e; i += 256)
        atomicAdd(&cnt[staging[sbase + i] & (BSIZE - 1)], 1);
    __syncthreads();
    sc[tid] = cnt[tid];
    sc[tid + 256] = cnt[tid + 256];
    __syncthreads();
    for (int s = 1; s < BSIZE; s <<= 1) {
        int i0 = tid, i1 = tid + 256;
        int v0 = (i0 >= s) ? sc[i0 - s] : 0;
        int v1 = (i1 >= s) ? sc[i1 - s] : 0;
        __syncthreads();
        sc[i0] += v0;
        sc[i1] += v1;
        __syncthreads();
    }
    int e0 = sc[tid] - cnt[tid];
    int e1 = sc[tid + 256] - cnt[tid + 256];
    cur[tid] = e0;
    cur[tid + 256] = e1;
    if (tid < nn) row_ptr[n0 + tid] = bb + e0;
    if (tid + 256 < nn) row_ptr[n0 + tid + 256] = bb + e1;
    __syncthreads();
    for (int i = tid; i < cnt_e; i += 256) {
        int v = staging[sbase + i];
        int off = atomicAdd(&cur[v & (BSIZE - 1)], 1);
        csr[bb + off] = v >> BSHIFT;
    }
}

// ---------------- weight packing into MFMA B-fragment order ----------------
__global__ __launch_bounds__(256) void k_packw(const float* __restrict__ pre_w,
                                               const float* __restrict__ conv_w1,
                                               const float* __restrict__ conv_w2,
                                               const float* __restrict__ post_w1,
                                               const float* __restrict__ post_w2,
                                               unsigned short* __restrict__ wp) {
    int g = blockIdx.x >> 1;
    int c = (blockIdx.x & 1) * 256 + threadIdx.x;   // 0..511
    const float* W;
    switch (g) {
        case 0: W = pre_w; break;
        case 1: W = conv_w1; break;
        case 2: W = conv_w2; break;
        case 3: W = conv_w1 + 4096; break;
        case 4: W = conv_w2 + 4096; break;
        case 5: W = conv_w1 + 8192; break;
        case 6: W = conv_w2 + 8192; break;
        case 7: W = post_w1; break;
        default: W = post_w2; break;
    }
    int nt = c >> 7, ks = (c >> 6) & 1, ln = c & 63;
    int n = nt * 16 + (ln & 15);
    unsigned short* dstp = wp + (size_t)g * 4096 + (size_t)c * 8;
#pragma unroll
    for (int j = 0; j < 8; j++) {
        int k = ks * 32 + (ln >> 4) * 8 + j;
        dstp[j] = f2bf(W[k * HD + n]);
    }
}

// ---------------- pre GEMM: h = bf16(x(f32) @ W + b) ----------------
__global__ __launch_bounds__(256, 4) void k_pre(const float* __restrict__ x,
                                                const unsigned short* __restrict__ wp0,
                                                const float* __restrict__ bias,
                                                unsigned short* __restrict__ h) {
    __shared__ char lds_all[4][16 * TS_BF];
    int tid = threadIdx.x, lane = tid & 63, wid = tid >> 6;
    int lg = lane >> 4, li = lane & 15;
    char* base = lds_all[wid];

    bf16x8 wf[4][2];
#pragma unroll
    for (int nt = 0; nt < 4; nt++)
#pragma unroll
        for (int ks = 0; ks < 2; ks++)
            wf[nt][ks] = __builtin_bit_cast(bf16x8,
                *(const short8*)(wp0 + ((size_t)((nt * 2 + ks) * 64 + lane)) * 8));
    float bb[4];
#pragma unroll
    for (int nt = 0; nt < 4; nt++) bb[nt] = bias[nt * 16 + li];

    int gwave = (blockIdx.x * 256 + tid) >> 6;
    int nwaves = (gridDim.x * 256) >> 6;
    for (int tile = gwave; tile < NTILE; tile += nwaves) {
        int row = tile * 16 + li;
        bf16x8 af[2];
#pragma unroll
        for (int ks = 0; ks < 2; ks++) {
            const float* p = x + (size_t)row * HD + ks * 32 + lg * 8;
            union { unsigned short u[8]; short8 s; } t;
#pragma unroll
            for (int j = 0; j < 8; j++) t.u[j] = f2bf(p[j]);
            af[ks] = __builtin_bit_cast(bf16x8, t.s);
        }
        f32x4 acc[4];
#pragma unroll
        for (int nt = 0; nt < 4; nt++) acc[nt] = (f32x4){0.f, 0.f, 0.f, 0.f};
#pragma unroll
        for (int ks = 0; ks < 2; ks++)
#pragma unroll
            for (int nt = 0; nt < 4; nt++)
                acc[nt] = __builtin_amdgcn_mfma_f32_16x16x32_bf16(af[ks], wf[nt][ks], acc[nt], 0, 0, 0);
#pragma unroll
        for (int nt = 0; nt < 4; nt++)
#pragma unroll
            for (int r = 0; r < 4; r++)
                *(unsigned short*)(base + (lg * 4 + r) * TS_BF + (nt * 16 + li) * 2)
                    = f2bf(acc[nt][r] + bb[nt]);
#pragma unroll
        for (int s = 0; s < 2; s++) {
            short8 t = *(short8*)(base + li * TS_BF + (s * 4 + lg) * 16);
            *(short8*)(h + (size_t)row * HD + (s * 4 + lg) * 8) = t;
        }
    }
}

// ---------------- fused MLP: LDS-resident weights (8 KB each) ---------------
template<bool STATS>
__global__ __launch_bounds__(256, 4) void k_fmlp(const unsigned short* __restrict__ in,
                                                 const unsigned short* __restrict__ wpa,
                                                 const unsigned short* __restrict__ wpb,
                                                 const float* __restrict__ b1,
                                                 const float* __restrict__ b2,
                                                 unsigned short* __restrict__ outp,
                                                 float* __restrict__ stats_out) {
    __shared__ char lds_all[4][16 * TS_BF];
    __shared__ unsigned short wl[2][4096];
    int tid = threadIdx.x, lane = tid & 63, wid = tid >> 6;
    int lg = lane >> 4, li = lane & 15;
    char* base = lds_all[wid];

    ((short8*)wl[0])[tid] = ((const short8*)wpa)[tid];
    ((short8*)wl[0])[tid + 256] = ((const short8*)wpa)[tid + 256];
    ((short8*)wl[1])[tid] = ((const short8*)wpb)[tid];
    ((short8*)wl[1])[tid + 256] = ((const short8*)wpb)[tid + 256];
    __syncthreads();

    float bb1[4], bb2[4];
#pragma unroll
    for (int nt = 0; nt < 4; nt++) {
        bb1[nt] = b1[nt * 16 + li];
        bb2[nt] = b2[nt * 16 + li];
    }

    float s1[4] = {0.f, 0.f, 0.f, 0.f}, s2[4] = {0.f, 0.f, 0.f, 0.f};
    int gwave = (blockIdx.x * 256 + tid) >> 6;
    int nwaves = (gridDim.x * 256) >> 6;
    for (int tile = gwave; tile < NTILE; tile += nwaves) {
        int row = tile * 16 + li;
        bf16x8 af[2];
#pragma unroll
        for (int ks = 0; ks < 2; ks++)
            af[ks] = __builtin_bit_cast(bf16x8,
                *(const short8*)(in + (size_t)row * HD + ks * 32 + lg * 8));
        f32x4 acc[4];
#pragma unroll
        for (int nt = 0; nt < 4; nt++) acc[nt] = (f32x4){0.f, 0.f, 0.f, 0.f};
#pragma unroll
        for (int ks = 0; ks < 2; ks++)
#pragma unroll
            for (int nt = 0; nt < 4; nt++) {
                bf16x8 wf = *(const bf16x8*)(&wl[0][(size_t)((nt * 2 + ks) * 64 + lane) * 8]);
                acc[nt] = __builtin_amdgcn_mfma_f32_16x16x32_bf16(af[ks], wf, acc[nt], 0, 0, 0);
            }
#pragma unroll
        for (int nt = 0; nt < 4; nt++)
#pragma unroll
            for (int r = 0; r < 4; r++)
                *(unsigned short*)(base + (lg * 4 + r) * TS_BF + (nt * 16 + li) * 2)
                    = f2bf(lrelu(acc[nt][r] + bb1[nt]));
        bf16x8 a2[2];
#pragma unroll
        for (int ks = 0; ks < 2; ks++)
            a2[ks] = *(bf16x8*)(base + li * TS_BF + (ks * 32 + lg * 8) * 2);
        f32x4 acc2[4];
#pragma unroll
        for (int nt = 0; nt < 4; nt++) acc2[nt] = (f32x4){0.f, 0.f, 0.f, 0.f};
#pragma unroll
        for (int ks = 0; ks < 2; ks++)
#pragma unroll
            for (int nt = 0; nt < 4; nt++) {
                bf16x8 wf = *(const bf16x8*)(&wl[1][(size_t)((nt * 2 + ks) * 64 + lane) * 8]);
                acc2[nt] = __builtin_amdgcn_mfma_f32_16x16x32_bf16(a2[ks], wf, acc2[nt], 0, 0, 0);
            }
#pragma unroll
        for (int nt = 0; nt < 4; nt++) {
#pragma unroll
            for (int r = 0; r < 4; r++) {
                float u = acc2[nt][r] + bb2[nt];
                if (STATS) { s1[nt] += u; s2[nt] += u * u; }
                *(unsigned short*)(base + (lg * 4 + r) * TS_BF + (nt * 16 + li) * 2)
                    = f2bf(u);
            }
        }
#pragma unroll
        for (int s = 0; s < 2; s++) {
            short8 t = *(short8*)(base + li * TS_BF + (s * 4 + lg) * 16);
            *(short8*)(outp + (size_t)row * HD + (s * 4 + lg) * 8) = t;
        }
    }
    if (STATS) {
#pragma unroll
        for (int nt = 0; nt < 4; nt++) {
            float a = s1[nt], b = s2[nt];
            a += __shfl_xor(a, 16); a += __shfl_xor(a, 32);
            b += __shfl_xor(b, 16); b += __shfl_xor(b, 32);
            if (lg == 0) {
                atomicAdd(&stats_out[nt * 16 + li], a);
                atomicAdd(&stats_out[64 + nt * 16 + li], b);
            }
        }
    }
}

// ---------------- 4-GEMM tail: LDS-resident weights (32 KB) ------------------
__global__ __launch_bounds__(256, 3) void k_fmlp4(const unsigned short* __restrict__ in,
                                                  const unsigned short* __restrict__ wpa,
                                                  const unsigned short* __restrict__ wpb,
                                                  const unsigned short* __restrict__ wpc,
                                                  const unsigned short* __restrict__ wpd,
                                                  const float* __restrict__ b1,
                                                  const float* __restrict__ b2,
                                                  const float* __restrict__ b3,
                                                  const float* __restrict__ b4,
                                                  float* __restrict__ outp) {
    __shared__ char lds_all[4][16 * TS_F32];
    __shared__ unsigned short wl[4][4096];
    int tid = threadIdx.x, lane = tid & 63, wid = tid >> 6;
    int lg = lane >> 4, li = lane & 15;
    char* base = lds_all[wid];

    ((short8*)wl[0])[tid] = ((const short8*)wpa)[tid];
    ((short8*)wl[0])[tid + 256] = ((const short8*)wpa)[tid + 256];
    ((short8*)wl[1])[tid] = ((const short8*)wpb)[tid];
    ((short8*)wl[1])[tid + 256] = ((const short8*)wpb)[tid + 256];
    ((short8*)wl[2])[tid] = ((const short8*)wpc)[tid];
    ((short8*)wl[2])[tid + 256] = ((const short8*)wpc)[tid + 256];
    ((short8*)wl[3])[tid] = ((const short8*)wpd)[tid];
    ((short8*)wl[3])[tid + 256] = ((const short8*)wpd)[tid + 256];
    __syncthreads();

    float bb1[4], bb2[4], bb3[4], bb4[4];
#pragma unroll
    for (int nt = 0; nt < 4; nt++) {
        bb1[nt] = b1[nt * 16 + li];
        bb2[nt] = b2[nt * 16 + li];
        bb3[nt] = b3[nt * 16 + li];
        bb4[nt] = b4[nt * 16 + li];
    }

    int gwave = (blockIdx.x * 256 + tid) >> 6;
    int nwaves = (gridDim.x * 256) >> 6;
    for (int tile = gwave; tile < NTILE; tile += nwaves) {
        int row = tile * 16 + li;
        bf16x8 af[2];
#pragma unroll
        for (int ks = 0; ks < 2; ks++)
            af[ks] = __builtin_bit_cast(bf16x8,
                *(const short8*)(in + (size_t)row * HD + ks * 32 + lg * 8));
        f32x4 acc[4];
#pragma unroll
        for (int nt = 0; nt < 4; nt++) acc[nt] = (f32x4){0.f, 0.f, 0.f, 0.f};
#pragma unroll
        for (int ks = 0; ks < 2; ks++)
#pragma unroll
            for (int nt = 0; nt < 4; nt++) {
                bf16x8 wf = *(const bf16x8*)(&wl[0][(size_t)((nt * 2 + ks) * 64 + lane) * 8]);
                acc[nt] = __builtin_amdgcn_mfma_f32_16x16x32_bf16(af[ks], wf, acc[nt], 0, 0, 0);
            }
#pragma unroll
        for (int nt = 0; nt < 4; nt++)
#pragma unroll
            for (int r = 0; r < 4; r++)
                *(unsigned short*)(base + (lg * 4 + r) * TS_BF + (nt * 16 + li) * 2)
                    = f2bf(lrelu(acc[nt][r] + bb1[nt]));
#pragma unroll
        for (int ks = 0; ks < 2; ks++)
            af[ks] = *(bf16x8*)(base + li * TS_BF + (ks * 32 + lg * 8) * 2);
#pragma unroll
        for (int nt = 0; nt < 4; nt++) acc[nt] = (f32x4){0.f, 0.f, 0.f, 0.f};
#pragma unroll
        for (int ks = 0; ks < 2; ks++)
#pragma unroll
            for (int nt = 0; nt < 4; nt++) {
                bf16x8 wf = *(const bf16x8*)(&wl[1][(size_t)((nt * 2 + ks) * 64 + lane) * 8]);
                acc[nt] = __builtin_amdgcn_mfma_f32_16x16x32_bf16(af[ks], wf, acc[nt], 0, 0, 0);
            }
#pragma unroll
        for (int nt = 0; nt < 4; nt++)
#pragma unroll
            for (int r = 0; r < 4; r++)
                *(unsigned short*)(base + (lg * 4 + r) * TS_BF + (nt * 16 + li) * 2)
                    = f2bf(acc[nt][r] + bb2[nt]);
#pragma unroll
        for (int ks = 0; ks < 2; ks++)
            af[ks] = *(bf16x8*)(base + li * TS_BF + (ks * 32 + lg * 8) * 2);
#pragma unroll
        for (int nt = 0; nt < 4; nt++) acc[nt] = (f32x4){0.f, 0.f, 0.f, 0.f};
#pragma unroll
        for (int ks = 0; ks < 2; ks++)
#pragma unroll
            for (int nt = 0; nt < 4; nt++) {
                bf16x8 wf = *(const bf16x8*)(&wl[2][(size_t)((nt * 2 + ks) * 64 + lane) * 8]);
                acc[nt] = __builtin_amdgcn_mfma_f32_16x16x32_bf16(af[ks], wf, acc[nt], 0, 0, 0);
            }
#pragma unroll
        for (int nt = 0; nt < 4; nt++)
#pragma unroll
            for (int r = 0; r < 4; r++)
                *(unsigned short*)(base + (lg * 4 + r) * TS_BF + (nt * 16 + li) * 2)
                    = f2bf(lrelu(acc[nt][r] + bb3[nt]));
#pragma unroll
        for (int ks = 0; ks < 2; ks++)
            af[ks] = *(bf16x8*)(base + li * TS_BF + (ks * 32 + lg * 8) * 2);
#pragma unroll
        for (int nt = 0; nt < 4; nt++) acc[nt] = (f32x4){0.f, 0.f, 0.f, 0.f};
#pragma unroll
        for (int ks = 0; ks < 2; ks++)
#pragma unroll
            for (int nt = 0; nt < 4; nt++) {
                bf16x8 wf = *(const bf16x8*)(&wl[3][(size_t)((nt * 2 + ks) * 64 + lane) * 8]);
                acc[nt] = __builtin_amdgcn_mfma_f32_16x16x32_bf16(af[ks], wf, acc[nt], 0, 0, 0);
            }
#pragma unroll
        for (int nt = 0; nt < 4; nt++)
#pragma unroll
            for (int r = 0; r < 4; r++)
                *(float*)(base + (lg * 4 + r) * TS_F32 + (nt * 16 + li) * 4)
                    = acc[nt][r] + bb4[nt];
#pragma unroll
        for (int s = 0; s < 4; s++) {
            f32x4 t = *(f32x4*)(base + li * TS_F32 + (s * 4 + lg) * 16);
            *(f32x4*)(outp + (size_t)row * HD + (s * 4 + lg) * 4) = t;
        }
    }
}

// ---------------- gather: 8-lane group per node, uint4 loads ----------------
// One vector-load instruction fetches 8 rows (8 groups x 8 lanes x 16B = 1KB);
// 8-deep unroll -> 64 rows in flight per wave (2x round-16).
__global__ __launch_bounds__(256, 6) void k_gather(const unsigned short* __restrict__ h,
                                                   const int* __restrict__ row_ptr,
                                                   const int* __restrict__ csr,
                                                   const float* __restrict__ bn_stats,
                                                   const float* __restrict__ bn_g,
                                                   const float* __restrict__ bn_b,
                                                   int apply_bn,
                                                   unsigned short* __restrict__ z) {
    int tid = threadIdx.x;
    int lane = tid & 63;
    int g = lane >> 3;              // node sub-group 0..7
    int fq = lane & 7;              // uint4 index within row (8 x 16B = 128B)
    int wave = (blockIdx.x * 256 + tid) >> 6;
    int node = wave * 8 + g;
    if (node >= NN) return;

    float sc[8], sh[8];
    if (apply_bn) {
        float inv = 1.f / (float)NN;
#pragma unroll
        for (int j = 0; j < 8; j++) {
            int f = fq * 8 + j;
            float mu = bn_stats[f] * inv;
            float var = bn_stats[64 + f] * inv - mu * mu;
            float s = rsqrtf(var + BN_EPS) * bn_g[f];
            sc[j] = s;
            sh[j] = bn_b[f] - mu * s;
        }
    }

    const uint4* hv = (const uint4*)h;   // row = 8 x uint4
    int r0 = row_ptr[node], re = row_ptr[node + 1];
    uint4 sv = hv[(size_t)node * 8 + fq];
    float aA[8], aB[8] = {0, 0, 0, 0, 0, 0, 0, 0};
    aA[0] = bflo(sv.x); aA[1] = bfhi(sv.x);
    aA[2] = bflo(sv.y); aA[3] = bfhi(sv.y);
    aA[4] = bflo(sv.z); aA[5] = bfhi(sv.z);
    aA[6] = bflo(sv.w); aA[7] = bfhi(sv.w);

    int e = r0;
    for (; e + 8 <= re; e += 8) {
        int i0 = csr[e], i1 = csr[e + 1], i2 = csr[e + 2], i3 = csr[e + 3];
        int i4 = csr[e + 4], i5 = csr[e + 5], i6 = csr[e + 6], i7 = csr[e + 7];
        uint4 v0 = hv[(size_t)i0 * 8 + fq];
        uint4 v1 = hv[(size_t)i1 * 8 + fq];
        uint4 v2 = hv[(size_t)i2 * 8 + fq];
        uint4 v3 = hv[(size_t)i3 * 8 + fq];
        uint4 v4 = hv[(size_t)i4 * 8 + fq];
        uint4 v5 = hv[(size_t)i5 * 8 + fq];
        uint4 v6 = hv[(size_t)i6 * 8 + fq];
        uint4 v7 = hv[(size_t)i7 * 8 + fq];
#define ACC(dst, v) \
        dst[0] += bflo(v.x); dst[1] += bfhi(v.x); \
        dst[2] += bflo(v.y); dst[3] += bfhi(v.y); \
        dst[4] += bflo(v.z); dst[5] += bfhi(v.z); \
        dst[6] += bflo(v.w); dst[7] += bfhi(v.w);
        ACC(aA, v0) ACC(aB, v1) ACC(aA, v2) ACC(aB, v3)
        ACC(aA, v4) ACC(aB, v5) ACC(aA, v6) ACC(aB, v7)
    }
    for (; e < re; e++) {
        uint4 v = hv[(size_t)csr[e] * 8 + fq];
        ACC(aA, v)
    }
#undef ACC
    float cnt = (float)(re - r0 + 1);
    unsigned short o[8];
#pragma unroll
    for (int j = 0; j < 8; j++) {
        float s = aA[j] + aB[j];
        if (apply_bn) s = fmaf(s, sc[j], cnt * sh[j]);
        o[j] = f2bf(s);
    }
    uint4 ov;
    ov.x = (unsigned)o[0] | ((unsigned)o[1] << 16);
    ov.y = (unsigned)o[2] | ((unsigned)o[3] << 16);
    ov.z = (unsigned)o[4] | ((unsigned)o[5] << 16);
    ov.w = (unsigned)o[6] | ((unsigned)o[7] << 16);
    ((uint4*)z)[(size_t)node * 8 + fq] = ov;
}

extern "C" void kernel_launch(void* const* d_in, const int* in_sizes, int n_in,
                              void* d_out, int out_size, void* d_ws, size_t ws_size,
                              hipStream_t stream) {
    const float* x = (const float*)d_in[0];
    const int* edge = (const int*)d_in[1];
    const float* pre_w = (const float*)d_in[2];
    const float* pre_b = (const float*)d_in[3];
    const float* conv_w1 = (const float*)d_in[4];
    const float* conv_b1 = (const float*)d_in[5];
    const float* conv_w2 = (const float*)d_in[6];
    const float* conv_b2 = (const float*)d_in[7];
    const float* bn_g = (const float*)d_in[8];
    const float* bn_b = (const float*)d_in[9];
    const float* post_w1 = (const float*)d_in[10];
    const float* post_b1 = (const float*)d_in[11];
    const float* post_w2 = (const float*)d_in[12];
    const float* post_b2 = (const float*)d_in[13];
    float* out = (float*)d_out;

    const int* src = edge;       // edge_index[0]
    const int* dst = edge + EE;  // edge_index[1]

    unsigned short* hH = (unsigned short*)d_ws;          // NN*64 bf16
    unsigned short* zZ = hH + (size_t)NN * HD;           // NN*64 bf16
    float* stats0 = (float*)(zZ + (size_t)NN * HD);      // 128 f32
    float* stats1 = stats0 + 128;                        // 128 f32
    unsigned short* wp = (unsigned short*)(stats1 + 128);// 9*4096 bf16
    int* row_ptr = (int*)(wp + 9 * 4096);                // NN+4 ints
    int* csr = row_ptr + NN + 4;                         // EE ints
    int* bcursor = csr + EE;                             // NBUCK (+pad)
    int* bbase = bcursor + 256;                          // NBUCK (+pad)
    int* staging = bbase + 256;                          // NBUCK*BCAP ints

    dim3 blk(256);
    dim3 gG(3125);   // 12500 waves x 8 nodes = 100000
    dim3 gM(782);    // 3128 waves, 2 tiles each

    // CSR build (bucketed counting sort)
    hipMemsetAsync(stats0, 0, 256 * sizeof(float), stream);
    hipLaunchKernelGGL(k_binit, dim3(1), blk, 0, stream, bcursor);
    hipLaunchKernelGGL(k_bucketa, dim3(NBLKA), blk, 0, stream, src, dst, bcursor, staging);
    hipLaunchKernelGGL(k_bscan, dim3(1), blk, 0, stream, bcursor, bbase, row_ptr);
    hipLaunchKernelGGL(k_bucketb, dim3(NBUCK), blk, 0, stream, staging, bcursor, bbase,
                       row_ptr, csr);

    // pack weights into MFMA fragment order
    hipLaunchKernelGGL(k_packw, dim3(18), blk, 0, stream,
                       pre_w, conv_w1, conv_w2, post_w1, post_w2, wp);

    // pre: x(f32) -> hH (bf16)
    hipLaunchKernelGGL(k_pre, gM, blk, 0, stream, x, wp + 0 * 4096, pre_b, hH);

    // layer 0: gather -> fused mlp (stats0)
    hipLaunchKernelGGL(k_gather, gG, blk, 0, stream, hH, row_ptr, csr,
                       (const float*)nullptr, (const float*)nullptr, (const float*)nullptr, 0, zZ);
    hipLaunchKernelGGL((k_fmlp<true>), gM, blk, 0, stream, zZ,
                       wp + 1 * 4096, wp + 2 * 4096, conv_b1, conv_b2, hH, stats0);

    // layer 1: gather(BN l0) -> fused mlp (stats1)
    hipLaunchKernelGGL(k_gather, gG, blk, 0, stream, hH, row_ptr, csr,
                       stats0, bn_g, bn_b, 1, zZ);
    hipLaunchKernelGGL((k_fmlp<true>), gM, blk, 0, stream, zZ,
                       wp + 3 * 4096, wp + 4 * 4096, conv_b1 + HD, conv_b2 + HD, hH, stats1);

    // layer 2: gather(BN l1) -> 4-GEMM tail -> out f32
    hipLaunchKernelGGL(k_gather, gG, blk, 0, stream, hH, row_ptr, csr,
                       stats1, bn_g + HD, bn_b + HD, 1, zZ);
    hipLaunchKernelGGL(k_fmlp4, gM, blk, 0, stream, zZ,
                       wp + 5 * 4096, wp + 6 * 4096, wp + 7 * 4096, wp + 8 * 4096,
                       conv_b1 + 2 * HD, conv_b2 + 2 * HD, post_b1, post_b2, out);
}

// Round 20
// 361.700 us; speedup vs baseline: 1.1145x; 1.1145x over previous
//
#include <hip/hip_runtime.h>
#include <hip/hip_bf16.h>

#define NN 100000      // nodes
#define EE 1600000     // edges
#define HD 64
#define SLOPE 0.01f
#define BN_EPS 1e-5f
#define TS_BF 144
#define TS_F32 272
#define NTILE (NN / 16)   // 6250

// bucketed CSR build
#define BSHIFT 9
#define BSIZE 512
#define NBUCK ((NN + BSIZE - 1) / BSIZE)   // 196
#define BCAP 16384
#define CHUNKE 8192
#define NBLKA ((EE + CHUNKE - 1) / CHUNKE) // 196

typedef __attribute__((ext_vector_type(8))) short short8;
typedef __attribute__((ext_vector_type(8))) __bf16 bf16x8;
typedef __attribute__((ext_vector_type(4))) float f32x4;

__device__ __forceinline__ float lrelu(float v) { return v > 0.f ? v : SLOPE * v; }
__device__ __forceinline__ float bflo(unsigned u) { return __uint_as_float(u << 16); }
__device__ __forceinline__ float bfhi(unsigned u) { return __uint_as_float(u & 0xFFFF0000u); }
__device__ __forceinline__ unsigned short f2bf(float f) {
    __hip_bfloat16 hb = __float2bfloat16(f);
    return *reinterpret_cast<unsigned short*>(&hb);
}

// ---------------- CSR build: bucketed two-pass counting sort ----------------
__global__ __launch_bounds__(256) void k_binit(int* __restrict__ bcursor) {
    int t = threadIdx.x;
    if (t < NBUCK) bcursor[t] = t * BCAP;
}

__global__ __launch_bounds__(256) void k_bucketa(const int* __restrict__ src,
                                                 const int* __restrict__ dst,
                                                 int* __restrict__ bcursor,
                                                 int* __restrict__ staging) {
    __shared__ int hist[NBUCK], base_l[NBUCK], cur_l[NBUCK];
    int tid = threadIdx.x;
    int base = blockIdx.x * CHUNKE;
    int nE = min(CHUNKE, EE - base);
    for (int i = tid; i < NBUCK; i += 256) hist[i] = 0;
    __syncthreads();
    for (int k = tid; k < nE; k += 256)
        atomicAdd(&hist[dst[base + k] >> BSHIFT], 1);
    __syncthreads();
    for (int i = tid; i < NBUCK; i += 256) {
        int h = hist[i];
        base_l[i] = h ? atomicAdd(&bcursor[i], h) : 0;
        cur_l[i] = 0;
    }
    __syncthreads();
    for (int k = tid; k < nE; k += 256) {
        int d = dst[base + k];
        int s = src[base + k];
        int b = d >> BSHIFT;
        int off = atomicAdd(&cur_l[b], 1);
        staging[base_l[b] + off] = (s << BSHIFT) | (d & (BSIZE - 1));
    }
}

__global__ __launch_bounds__(256) void k_bscan(const int* __restrict__ bcursor,
                                               int* __restrict__ bbase,
                                               int* __restrict__ row_ptr) {
    __shared__ int sc[256], cnt[256];
    int tid = threadIdx.x;
    int c = (tid < NBUCK) ? (bcursor[tid] - tid * BCAP) : 0;
    cnt[tid] = c;
    sc[tid] = c;
    __syncthreads();
    for (int s = 1; s < 256; s <<= 1) {
        int v = (tid >= s) ? sc[tid - s] : 0;
        __syncthreads();
        sc[tid] += v;
        __syncthreads();
    }
    if (tid < NBUCK) bbase[tid] = sc[tid] - cnt[tid];
    if (tid == 0) row_ptr[NN] = EE;
}

__global__ __launch_bounds__(256) void k_bucketb(const int* __restrict__ staging,
                                                 const int* __restrict__ bcursor,
                                                 const int* __restrict__ bbase,
                                                 int* __restrict__ row_ptr,
                                                 int* __restrict__ csr) {
    __shared__ int cnt[BSIZE], sc[BSIZE], cur[BSIZE];
    int b = blockIdx.x, tid = threadIdx.x;
    int cnt_e = bcursor[b] - b * BCAP;
    int sbase = b * BCAP;
    int n0 = b * BSIZE;
    int nn = min(BSIZE, NN - n0);
    int bb = bbase[b];
    cnt[tid] = 0;
    cnt[tid + 256] = 0;
    __syncthreads();
    for (int i = tid; i < cnt_e; i += 256)
        atomicAdd(&cnt[staging[sbase + i] & (BSIZE - 1)], 1);
    __syncthreads();
    sc[tid] = cnt[tid];
    sc[tid + 256] = cnt[tid + 256];
    __syncthreads();
    for (int s = 1; s < BSIZE; s <<= 1) {
        int i0 = tid, i1 = tid + 256;
        int v0 = (i0 >= s) ? sc[i0 - s] : 0;
        int v1 = (i1 >= s) ? sc[i1 - s] : 0;
        __syncthreads();
        sc[i0] += v0;
        sc[i1] += v1;
        __syncthreads();
    }
    int e0 = sc[tid] - cnt[tid];
    int e1 = sc[tid + 256] - cnt[tid + 256];
    cur[tid] = e0;
    cur[tid + 256] = e1;
    if (tid < nn) row_ptr[n0 + tid] = bb + e0;
    if (tid + 256 < nn) row_ptr[n0 + tid + 256] = bb + e1;
    __syncthreads();
    for (int i = tid; i < cnt_e; i += 256) {
        int v = staging[sbase + i];
        int off = atomicAdd(&cur[v & (BSIZE - 1)], 1);
        csr[bb + off] = v >> BSHIFT;
    }
}

// ---------------- weight packing into MFMA B-fragment order ----------------
__global__ __launch_bounds__(256) void k_packw(const float* __restrict__ pre_w,
                                               const float* __restrict__ conv_w1,
                                               const float* __restrict__ conv_w2,
                                               const float* __restrict__ post_w1,
                                               const float* __restrict__ post_w2,
                                               unsigned short* __restrict__ wp) {
    int g = blockIdx.x >> 1;
    int c = (blockIdx.x & 1) * 256 + threadIdx.x;   // 0..511
    const float* W;
    switch (g) {
        case 0: W = pre_w; break;
        case 1: W = conv_w1; break;
        case 2: W = conv_w2; break;
        case 3: W = conv_w1 + 4096; break;
        case 4: W = conv_w2 + 4096; break;
        case 5: W = conv_w1 + 8192; break;
        case 6: W = conv_w2 + 8192; break;
        case 7: W = post_w1; break;
        default: W = post_w2; break;
    }
    int nt = c >> 7, ks = (c >> 6) & 1, ln = c & 63;
    int n = nt * 16 + (ln & 15);
    unsigned short* dstp = wp + (size_t)g * 4096 + (size_t)c * 8;
#pragma unroll
    for (int j = 0; j < 8; j++) {
        int k = ks * 32 + (ln >> 4) * 8 + j;
        dstp[j] = f2bf(W[k * HD + n]);
    }
}

// ---------------- pre GEMM: h = bf16(x(f32) @ W + b) ----------------
__global__ __launch_bounds__(256, 4) void k_pre(const float* __restrict__ x,
                                                const unsigned short* __restrict__ wp0,
                                                const float* __restrict__ bias,
                                                unsigned short* __restrict__ h) {
    __shared__ char lds_all[4][16 * TS_BF];
    int tid = threadIdx.x, lane = tid & 63, wid = tid >> 6;
    int lg = lane >> 4, li = lane & 15;
    char* base = lds_all[wid];

    bf16x8 wf[4][2];
#pragma unroll
    for (int nt = 0; nt < 4; nt++)
#pragma unroll
        for (int ks = 0; ks < 2; ks++)
            wf[nt][ks] = __builtin_bit_cast(bf16x8,
                *(const short8*)(wp0 + ((size_t)((nt * 2 + ks) * 64 + lane)) * 8));
    float bb[4];
#pragma unroll
    for (int nt = 0; nt < 4; nt++) bb[nt] = bias[nt * 16 + li];

    int gwave = (blockIdx.x * 256 + tid) >> 6;
    int nwaves = (gridDim.x * 256) >> 6;
    for (int tile = gwave; tile < NTILE; tile += nwaves) {
        int row = tile * 16 + li;
        bf16x8 af[2];
#pragma unroll
        for (int ks = 0; ks < 2; ks++) {
            const float* p = x + (size_t)row * HD + ks * 32 + lg * 8;
            union { unsigned short u[8]; short8 s; } t;
#pragma unroll
            for (int j = 0; j < 8; j++) t.u[j] = f2bf(p[j]);
            af[ks] = __builtin_bit_cast(bf16x8, t.s);
        }
        f32x4 acc[4];
#pragma unroll
        for (int nt = 0; nt < 4; nt++) acc[nt] = (f32x4){0.f, 0.f, 0.f, 0.f};
#pragma unroll
        for (int ks = 0; ks < 2; ks++)
#pragma unroll
            for (int nt = 0; nt < 4; nt++)
                acc[nt] = __builtin_amdgcn_mfma_f32_16x16x32_bf16(af[ks], wf[nt][ks], acc[nt], 0, 0, 0);
#pragma unroll
        for (int nt = 0; nt < 4; nt++)
#pragma unroll
            for (int r = 0; r < 4; r++)
                *(unsigned short*)(base + (lg * 4 + r) * TS_BF + (nt * 16 + li) * 2)
                    = f2bf(acc[nt][r] + bb[nt]);
#pragma unroll
        for (int s = 0; s < 2; s++) {
            short8 t = *(short8*)(base + li * TS_BF + (s * 4 + lg) * 16);
            *(short8*)(h + (size_t)row * HD + (s * 4 + lg) * 8) = t;
        }
    }
}

// ---------------- fused MLP: LDS-resident weights (8 KB each) ---------------
template<bool STATS>
__global__ __launch_bounds__(256, 4) void k_fmlp(const unsigned short* __restrict__ in,
                                                 const unsigned short* __restrict__ wpa,
                                                 const unsigned short* __restrict__ wpb,
                                                 const float* __restrict__ b1,
                                                 const float* __restrict__ b2,
                                                 unsigned short* __restrict__ outp,
                                                 float* __restrict__ stats_out) {
    __shared__ char lds_all[4][16 * TS_BF];
    __shared__ unsigned short wl[2][4096];
    int tid = threadIdx.x, lane = tid & 63, wid = tid >> 6;
    int lg = lane >> 4, li = lane & 15;
    char* base = lds_all[wid];

    ((short8*)wl[0])[tid] = ((const short8*)wpa)[tid];
    ((short8*)wl[0])[tid + 256] = ((const short8*)wpa)[tid + 256];
    ((short8*)wl[1])[tid] = ((const short8*)wpb)[tid];
    ((short8*)wl[1])[tid + 256] = ((const short8*)wpb)[tid + 256];
    __syncthreads();

    float bb1[4], bb2[4];
#pragma unroll
    for (int nt = 0; nt < 4; nt++) {
        bb1[nt] = b1[nt * 16 + li];
        bb2[nt] = b2[nt * 16 + li];
    }

    float s1[4] = {0.f, 0.f, 0.f, 0.f}, s2[4] = {0.f, 0.f, 0.f, 0.f};
    int gwave = (blockIdx.x * 256 + tid) >> 6;
    int nwaves = (gridDim.x * 256) >> 6;
    for (int tile = gwave; tile < NTILE; tile += nwaves) {
        int row = tile * 16 + li;
        bf16x8 af[2];
#pragma unroll
        for (int ks = 0; ks < 2; ks++)
            af[ks] = __builtin_bit_cast(bf16x8,
                *(const short8*)(in + (size_t)row * HD + ks * 32 + lg * 8));
        f32x4 acc[4];
#pragma unroll
        for (int nt = 0; nt < 4; nt++) acc[nt] = (f32x4){0.f, 0.f, 0.f, 0.f};
#pragma unroll
        for (int ks = 0; ks < 2; ks++)
#pragma unroll
            for (int nt = 0; nt < 4; nt++) {
                bf16x8 wf = *(const bf16x8*)(&wl[0][(size_t)((nt * 2 + ks) * 64 + lane) * 8]);
                acc[nt] = __builtin_amdgcn_mfma_f32_16x16x32_bf16(af[ks], wf, acc[nt], 0, 0, 0);
            }
#pragma unroll
        for (int nt = 0; nt < 4; nt++)
#pragma unroll
            for (int r = 0; r < 4; r++)
                *(unsigned short*)(base + (lg * 4 + r) * TS_BF + (nt * 16 + li) * 2)
                    = f2bf(lrelu(acc[nt][r] + bb1[nt]));
        bf16x8 a2[2];
#pragma unroll
        for (int ks = 0; ks < 2; ks++)
            a2[ks] = *(bf16x8*)(base + li * TS_BF + (ks * 32 + lg * 8) * 2);
        f32x4 acc2[4];
#pragma unroll
        for (int nt = 0; nt < 4; nt++) acc2[nt] = (f32x4){0.f, 0.f, 0.f, 0.f};
#pragma unroll
        for (int ks = 0; ks < 2; ks++)
#pragma unroll
            for (int nt = 0; nt < 4; nt++) {
                bf16x8 wf = *(const bf16x8*)(&wl[1][(size_t)((nt * 2 + ks) * 64 + lane) * 8]);
                acc2[nt] = __builtin_amdgcn_mfma_f32_16x16x32_bf16(a2[ks], wf, acc2[nt], 0, 0, 0);
            }
#pragma unroll
        for (int nt = 0; nt < 4; nt++) {
#pragma unroll
            for (int r = 0; r < 4; r++) {
                float u = acc2[nt][r] + bb2[nt];
                if (STATS) { s1[nt] += u; s2[nt] += u * u; }
                *(unsigned short*)(base + (lg * 4 + r) * TS_BF + (nt * 16 + li) * 2)
                    = f2bf(u);
            }
        }
#pragma unroll
        for (int s = 0; s < 2; s++) {
            short8 t = *(short8*)(base + li * TS_BF + (s * 4 + lg) * 16);
            *(short8*)(outp + (size_t)row * HD + (s * 4 + lg) * 8) = t;
        }
    }
    if (STATS) {
#pragma unroll
        for (int nt = 0; nt < 4; nt++) {
            float a = s1[nt], b = s2[nt];
            a += __shfl_xor(a, 16); a += __shfl_xor(a, 32);
            b += __shfl_xor(b, 16); b += __shfl_xor(b, 32);
            if (lg == 0) {
                atomicAdd(&stats_out[nt * 16 + li], a);
                atomicAdd(&stats_out[64 + nt * 16 + li], b);
            }
        }
    }
}

// ---------------- 4-GEMM tail: LDS-resident weights (32 KB) ------------------
__global__ __launch_bounds__(256, 3) void k_fmlp4(const unsigned short* __restrict__ in,
                                                  const unsigned short* __restrict__ wpa,
                                                  const unsigned short* __restrict__ wpb,
                                                  const unsigned short* __restrict__ wpc,
                                                  const unsigned short* __restrict__ wpd,
                                                  const float* __restrict__ b1,
                                                  const float* __restrict__ b2,
                                                  const float* __restrict__ b3,
                                                  const float* __restrict__ b4,
                                                  float* __restrict__ outp) {
    __shared__ char lds_all[4][16 * TS_F32];
    __shared__ unsigned short wl[4][4096];
    int tid = threadIdx.x, lane = tid & 63, wid = tid >> 6;
    int lg = lane >> 4, li = lane & 15;
    char* base = lds_all[wid];

    ((short8*)wl[0])[tid] = ((const short8*)wpa)[tid];
    ((short8*)wl[0])[tid + 256] = ((const short8*)wpa)[tid + 256];
    ((short8*)wl[1])[tid] = ((const short8*)wpb)[tid];
    ((short8*)wl[1])[tid + 256] = ((const short8*)wpb)[tid + 256];
    ((short8*)wl[2])[tid] = ((const short8*)wpc)[tid];
    ((short8*)wl[2])[tid + 256] = ((const short8*)wpc)[tid + 256];
    ((short8*)wl[3])[tid] = ((const short8*)wpd)[tid];
    ((short8*)wl[3])[tid + 256] = ((const short8*)wpd)[tid + 256];
    __syncthreads();

    float bb1[4], bb2[4], bb3[4], bb4[4];
#pragma unroll
    for (int nt = 0; nt < 4; nt++) {
        bb1[nt] = b1[nt * 16 + li];
        bb2[nt] = b2[nt * 16 + li];
        bb3[nt] = b3[nt * 16 + li];
        bb4[nt] = b4[nt * 16 + li];
    }

    int gwave = (blockIdx.x * 256 + tid) >> 6;
    int nwaves = (gridDim.x * 256) >> 6;
    for (int tile = gwave; tile < NTILE; tile += nwaves) {
        int row = tile * 16 + li;
        bf16x8 af[2];
#pragma unroll
        for (int ks = 0; ks < 2; ks++)
            af[ks] = __builtin_bit_cast(bf16x8,
                *(const short8*)(in + (size_t)row * HD + ks * 32 + lg * 8));
        f32x4 acc[4];
#pragma unroll
        for (int nt = 0; nt < 4; nt++) acc[nt] = (f32x4){0.f, 0.f, 0.f, 0.f};
#pragma unroll
        for (int ks = 0; ks < 2; ks++)
#pragma unroll
            for (int nt = 0; nt < 4; nt++) {
                bf16x8 wf = *(const bf16x8*)(&wl[0][(size_t)((nt * 2 + ks) * 64 + lane) * 8]);
                acc[nt] = __builtin_amdgcn_mfma_f32_16x16x32_bf16(af[ks], wf, acc[nt], 0, 0, 0);
            }
#pragma unroll
        for (int nt = 0; nt < 4; nt++)
#pragma unroll
            for (int r = 0; r < 4; r++)
                *(unsigned short*)(base + (lg * 4 + r) * TS_BF + (nt * 16 + li) * 2)
                    = f2bf(lrelu(acc[nt][r] + bb1[nt]));
#pragma unroll
        for (int ks = 0; ks < 2; ks++)
            af[ks] = *(bf16x8*)(base + li * TS_BF + (ks * 32 + lg * 8) * 2);
#pragma unroll
        for (int nt = 0; nt < 4; nt++) acc[nt] = (f32x4){0.f, 0.f, 0.f, 0.f};
#pragma unroll
        for (int ks = 0; ks < 2; ks++)
#pragma unroll
            for (int nt = 0; nt < 4; nt++) {
                bf16x8 wf = *(const bf16x8*)(&wl[1][(size_t)((nt * 2 + ks) * 64 + lane) * 8]);
                acc[nt] = __builtin_amdgcn_mfma_f32_16x16x32_bf16(af[ks], wf, acc[nt], 0, 0, 0);
            }
#pragma unroll
        for (int nt = 0; nt < 4; nt++)
#pragma unroll
            for (int r = 0; r < 4; r++)
                *(unsigned short*)(base + (lg * 4 + r) * TS_BF + (nt * 16 + li) * 2)
                    = f2bf(acc[nt][r] + bb2[nt]);
#pragma unroll
        for (int ks = 0; ks < 2; ks++)
            af[ks] = *(bf16x8*)(base + li * TS_BF + (ks * 32 + lg * 8) * 2);
#pragma unroll
        for (int nt = 0; nt < 4; nt++) acc[nt] = (f32x4){0.f, 0.f, 0.f, 0.f};
#pragma unroll
        for (int ks = 0; ks < 2; ks++)
#pragma unroll
            for (int nt = 0; nt < 4; nt++) {
                bf16x8 wf = *(const bf16x8*)(&wl[2][(size_t)((nt * 2 + ks) * 64 + lane) * 8]);
                acc[nt] = __builtin_amdgcn_mfma_f32_16x16x32_bf16(af[ks], wf, acc[nt], 0, 0, 0);
            }
#pragma unroll
        for (int nt = 0; nt < 4; nt++)
#pragma unroll
            for (int r = 0; r < 4; r++)
                *(unsigned short*)(base + (lg * 4 + r) * TS_BF + (nt * 16 + li) * 2)
                    = f2bf(lrelu(acc[nt][r] + bb3[nt]));
#pragma unroll
        for (int ks = 0; ks < 2; ks++)
            af[ks] = *(bf16x8*)(base + li * TS_BF + (ks * 32 + lg * 8) * 2);
#pragma unroll
        for (int nt = 0; nt < 4; nt++) acc[nt] = (f32x4){0.f, 0.f, 0.f, 0.f};
#pragma unroll
        for (int ks = 0; ks < 2; ks++)
#pragma unroll
            for (int nt = 0; nt < 4; nt++) {
                bf16x8 wf = *(const bf16x8*)(&wl[3][(size_t)((nt * 2 + ks) * 64 + lane) * 8]);
                acc[nt] = __builtin_amdgcn_mfma_f32_16x16x32_bf16(af[ks], wf, acc[nt], 0, 0, 0);
            }
#pragma unroll
        for (int nt = 0; nt < 4; nt++)
#pragma unroll
            for (int r = 0; r < 4; r++)
                *(float*)(base + (lg * 4 + r) * TS_F32 + (nt * 16 + li) * 4)
                    = acc[nt][r] + bb4[nt];
#pragma unroll
        for (int s = 0; s < 4; s++) {
            f32x4 t = *(f32x4*)(base + li * TS_F32 + (s * 4 + lg) * 16);
            *(f32x4*)(outp + (size_t)row * HD + (s * 4 + lg) * 4) = t;
        }
    }
}

// ---------------- gather (bf16): 16-lane/node uint2, 8-deep, 8 waves/SIMD ---
__global__ __launch_bounds__(256, 8) void k_gather(const unsigned short* __restrict__ h,
                                                   const int* __restrict__ row_ptr,
                                                   const int* __restrict__ csr,
                                                   const float* __restrict__ bn_stats,
                                                   const float* __restrict__ bn_g,
                                                   const float* __restrict__ bn_b,
                                                   int apply_bn,
                                                   unsigned short* __restrict__ z) {
    int tid = threadIdx.x;
    int lane = tid & 63;
    int g = lane >> 4;
    int fq = lane & 15;
    int wave = (blockIdx.x * 256 + tid) >> 6;
    int node = wave * 4 + g;
    if (node >= NN) return;

    float sc[4] = {1.f, 1.f, 1.f, 1.f}, sh[4] = {0.f, 0.f, 0.f, 0.f};
    if (apply_bn) {
        float inv = 1.f / (float)NN;
#pragma unroll
        for (int j = 0; j < 4; j++) {
            int f = fq * 4 + j;
            float mu = bn_stats[f] * inv;
            float var = bn_stats[64 + f] * inv - mu * mu;
            float s = rsqrtf(var + BN_EPS) * bn_g[f];
            sc[j] = s;
            sh[j] = bn_b[f] - mu * s;
        }
    }

    const uint2* hv = (const uint2*)h;
    int r0 = row_ptr[node], re = row_ptr[node + 1];
    uint2 sv = hv[(size_t)node * 16 + fq];
    float a0[4], a1[4] = {0, 0, 0, 0}, a2[4] = {0, 0, 0, 0}, a3[4] = {0, 0, 0, 0};
    a0[0] = bflo(sv.x); a0[1] = bfhi(sv.x); a0[2] = bflo(sv.y); a0[3] = bfhi(sv.y);

    int e = r0;
    for (; e + 8 <= re; e += 8) {
        int i0 = csr[e], i1 = csr[e + 1], i2 = csr[e + 2], i3 = csr[e + 3];
        int i4 = csr[e + 4], i5 = csr[e + 5], i6 = csr[e + 6], i7 = csr[e + 7];
        uint2 v0 = hv[(size_t)i0 * 16 + fq];
        uint2 v1 = hv[(size_t)i1 * 16 + fq];
        uint2 v2 = hv[(size_t)i2 * 16 + fq];
        uint2 v3 = hv[(size_t)i3 * 16 + fq];
        uint2 v4 = hv[(size_t)i4 * 16 + fq];
        uint2 v5 = hv[(size_t)i5 * 16 + fq];
        uint2 v6 = hv[(size_t)i6 * 16 + fq];
        uint2 v7 = hv[(size_t)i7 * 16 + fq];
        a0[0] += bflo(v0.x); a0[1] += bfhi(v0.x); a0[2] += bflo(v0.y); a0[3] += bfhi(v0.y);
        a1[0] += bflo(v1.x); a1[1] += bfhi(v1.x); a1[2] += bflo(v1.y); a1[3] += bfhi(v1.y);
        a2[0] += bflo(v2.x); a2[1] += bfhi(v2.x); a2[2] += bflo(v2.y); a2[3] += bfhi(v2.y);
        a3[0] += bflo(v3.x); a3[1] += bfhi(v3.x); a3[2] += bflo(v3.y); a3[3] += bfhi(v3.y);
        a0[0] += bflo(v4.x); a0[1] += bfhi(v4.x); a0[2] += bflo(v4.y); a0[3] += bfhi(v4.y);
        a1[0] += bflo(v5.x); a1[1] += bfhi(v5.x); a1[2] += bflo(v5.y); a1[3] += bfhi(v5.y);
        a2[0] += bflo(v6.x); a2[1] += bfhi(v6.x); a2[2] += bflo(v6.y); a2[3] += bfhi(v6.y);
        a3[0] += bflo(v7.x); a3[1] += bfhi(v7.x); a3[2] += bflo(v7.y); a3[3] += bfhi(v7.y);
    }
    for (; e < re; e++) {
        uint2 v = hv[(size_t)csr[e] * 16 + fq];
        a0[0] += bflo(v.x); a0[1] += bfhi(v.x); a0[2] += bflo(v.y); a0[3] += bfhi(v.y);
    }
    float cnt = (float)(re - r0 + 1);
    unsigned short o[4];
#pragma unroll
    for (int j = 0; j < 4; j++) {
        float s = ((a0[j] + a1[j]) + (a2[j] + a3[j]));
        if (apply_bn) s = fmaf(s, sc[j], cnt * sh[j]);
        o[j] = f2bf(s);
    }
    uint2 ov;
    ov.x = (unsigned)o[0] | ((unsigned)o[1] << 16);
    ov.y = (unsigned)o[2] | ((unsigned)o[3] << 16);
    ((uint2*)z)[(size_t)node * 16 + fq] = ov;
}

extern "C" void kernel_launch(void* const* d_in, const int* in_sizes, int n_in,
                              void* d_out, int out_size, void* d_ws, size_t ws_size,
                              hipStream_t stream) {
    const float* x = (const float*)d_in[0];
    const int* edge = (const int*)d_in[1];
    const float* pre_w = (const float*)d_in[2];
    const float* pre_b = (const float*)d_in[3];
    const float* conv_w1 = (const float*)d_in[4];
    const float* conv_b1 = (const float*)d_in[5];
    const float* conv_w2 = (const float*)d_in[6];
    const float* conv_b2 = (const float*)d_in[7];
    const float* bn_g = (const float*)d_in[8];
    const float* bn_b = (const float*)d_in[9];
    const float* post_w1 = (const float*)d_in[10];
    const float* post_b1 = (const float*)d_in[11];
    const float* post_w2 = (const float*)d_in[12];
    const float* post_b2 = (const float*)d_in[13];
    float* out = (float*)d_out;

    const int* src = edge;       // edge_index[0]
    const int* dst = edge + EE;  // edge_index[1]

    unsigned short* hH = (unsigned short*)d_ws;          // NN*64 bf16
    unsigned short* zZ = hH + (size_t)NN * HD;           // NN*64 bf16
    float* stats0 = (float*)(zZ + (size_t)NN * HD);      // 128 f32
    float* stats1 = stats0 + 128;                        // 128 f32
    unsigned short* wp = (unsigned short*)(stats1 + 128);// 9*4096 bf16
    int* row_ptr = (int*)(wp + 9 * 4096);                // NN+4 ints
    int* csr = row_ptr + NN + 4;                         // EE ints
    int* bcursor = csr + EE;                             // NBUCK (+pad)
    int* bbase = bcursor + 256;                          // NBUCK (+pad)
    int* staging = bbase + 256;                          // NBUCK*BCAP ints

    dim3 blk(256);
    dim3 gG(6250), gM(782);

    // CSR build (bucketed counting sort)
    hipMemsetAsync(stats0, 0, 256 * sizeof(float), stream);
    hipLaunchKernelGGL(k_binit, dim3(1), blk, 0, stream, bcursor);
    hipLaunchKernelGGL(k_bucketa, dim3(NBLKA), blk, 0, stream, src, dst, bcursor, staging);
    hipLaunchKernelGGL(k_bscan, dim3(1), blk, 0, stream, bcursor, bbase, row_ptr);
    hipLaunchKernelGGL(k_bucketb, dim3(NBUCK), blk, 0, stream, staging, bcursor, bbase,
                       row_ptr, csr);

    // pack weights into MFMA fragment order
    hipLaunchKernelGGL(k_packw, dim3(18), blk, 0, stream,
                       pre_w, conv_w1, conv_w2, post_w1, post_w2, wp);

    // pre: x(f32) -> hH (bf16)
    hipLaunchKernelGGL(k_pre, gM, blk, 0, stream, x, wp + 0 * 4096, pre_b, hH);

    // layer 0: gather -> fused mlp (stats0)
    hipLaunchKernelGGL(k_gather, gG, blk, 0, stream, hH, row_ptr, csr,
                       (const float*)nullptr, (const float*)nullptr, (const float*)nullptr, 0, zZ);
    hipLaunchKernelGGL((k_fmlp<true>), gM, blk, 0, stream, zZ,
                       wp + 1 * 4096, wp + 2 * 4096, conv_b1, conv_b2, hH, stats0);

    // layer 1: gather(BN l0) -> fused mlp (stats1)
    hipLaunchKernelGGL(k_gather, gG, blk, 0, stream, hH, row_ptr, csr,
                       stats0, bn_g, bn_b, 1, zZ);
    hipLaunchKernelGGL((k_fmlp<true>), gM, blk, 0, stream, zZ,
                       wp + 3 * 4096, wp + 4 * 4096, conv_b1 + HD, conv_b2 + HD, hH, stats1);

    // layer 2: gather(BN l1) -> 4-GEMM tail -> out f32
    hipLaunchKernelGGL(k_gather, gG, blk, 0, stream, hH, row_ptr, csr,
                       stats1, bn_g + HD, bn_b + HD, 1, zZ);
    hipLaunchKernelGGL(k_fmlp4, gM, blk, 0, stream, zZ,
                       wp + 5 * 4096, wp + 6 * 4096, wp + 7 * 4096, wp + 8 * 4096,
                       conv_b1 + 2 * HD, conv_b2 + 2 * HD, post_b1, post_b2, out);
}